// Round 7
// baseline (975.951 us; speedup 1.0000x reference)
//
#include <hip/hip_runtime.h>

#define VQ_B 32
#define VQ_D 64
#define VQ_L 4096
#define VQ_N 1024
#define VQ_R (VQ_B * VQ_L)            /* 131072 rows */
#define VQ_ZQ ((size_t)VQ_R * VQ_D)   /* 8388608 z_q elements */
#define MAIN_BLOCK 256
#define MAIN_GRID (VQ_R / MAIN_BLOCK) /* 512 (epilogue grid) */
#define NSEG 4
#define SEG_C (VQ_N / NSEG)           /* 256 codes per segment */
#define NT 16                         /* code-tile: 16 accumulators */
#define KC 4                          /* k-chunk: 4 z values live */
#define ROWS 64                       /* rows per block (= lanes) */
#define DGRID (VQ_R / ROWS)           /* 2048 row-blocks */

typedef __attribute__((ext_vector_type(16))) float f32x16;

/* ---- norm-of-embedding kernel (validated rounds 1-6, unchanged) ---- */
#define ZVE(i) ((i) < 16 ? zvA[(i) & 15] : (i) < 32 ? zvB[(i) & 15] \
               : (i) < 48 ? zvC[(i) & 15] : zvD[(i) & 15])
#define SQB(x) ({ float s_ = (x) * (x); asm volatile("" : "+v"(s_)); s_; })
#define NP_PAIRWISE64_SQ(dst)                                                  \
    do {                                                                       \
        float r0 = SQB(ZVE(0)), r1 = SQB(ZVE(1)), r2 = SQB(ZVE(2)),            \
              r3 = SQB(ZVE(3)), r4 = SQB(ZVE(4)), r5 = SQB(ZVE(5)),            \
              r6 = SQB(ZVE(6)), r7 = SQB(ZVE(7));                              \
        _Pragma("unroll")                                                      \
        for (int i_ = 1; i_ < 8; ++i_) {                                       \
            r0 += SQB(ZVE(8 * i_ + 0)); r1 += SQB(ZVE(8 * i_ + 1));            \
            r2 += SQB(ZVE(8 * i_ + 2)); r3 += SQB(ZVE(8 * i_ + 3));            \
            r4 += SQB(ZVE(8 * i_ + 4)); r5 += SQB(ZVE(8 * i_ + 5));            \
            r6 += SQB(ZVE(8 * i_ + 6)); r7 += SQB(ZVE(8 * i_ + 7));            \
        }                                                                      \
        dst = ((r0 + r1) + (r2 + r3)) + ((r4 + r5) + (r6 + r7));               \
    } while (0)

__global__ void vq_norme(const float* __restrict__ emb, float* __restrict__ nE) {
    const int c = blockIdx.x * blockDim.x + threadIdx.x;
    if (c >= VQ_N) return;
    const float* ec = emb + (c << 6);
    f32x16 zvA, zvB, zvC, zvD;
#pragma unroll
    for (int d = 0; d < 16; ++d) {
        zvA[d] = ec[d];
        zvB[d] = ec[d + 16];
        zvC[d] = ec[d + 32];
        zvD[d] = ec[d + 48];
    }
    float s;
    NP_PAIRWISE64_SQ(s);
    nE[c] = s;
}

/* ---- distance kernel: 4 waves share one 64-row z tile ----
   Block = 256 threads; wave w scans codebook segment w. LDS tile
   zs[d][lane] (16 KB) amortized over 4 waves -> VGPR-capped occupancy.
   zs reads: addr = d*256B + lane*4B -> 2 lanes/bank, conflict-free.
   Per-code arithmetic bitwise identical to validated rounds: numpy
   8-acc szz (d = 8i+j ascending, squares rounded pre-add), single-acc
   strictly-ascending-k fmaf chain, strict-< ascending tie-break. */
__global__ __launch_bounds__(4 * ROWS, 4) void vq_dist(
    const float* __restrict__ z, const float* __restrict__ emb,
    const float* __restrict__ nE, float2* __restrict__ cand)
{
    __shared__ float zs[VQ_D * ROWS];  /* 16 KB: [d][lane] */
    const int w = threadIdx.x >> 6;    /* wave = codebook segment */
    const int lane = threadIdx.x & 63;
    const int r = blockIdx.x * ROWS + lane;
    const int b = r >> 12;
    const int l = r & (VQ_L - 1);
    const float* zp = z + ((size_t)b << 18) + l;   /* z[b, d, l], d-stride 4096 */

    /* cooperative stage: wave w loads d in [16w, 16w+16), coalesced */
#pragma unroll
    for (int j = 0; j < 16; ++j) {
        const int d = (w << 4) + j;
        zs[d * ROWS + lane] = zp[(size_t)d << 12];
    }
    __syncthreads();

    /* szz from LDS, numpy 8-acc pairwise order (identical bits) */
    float a8[8];
#pragma unroll
    for (int j = 0; j < 8; ++j) {
        const float v = zs[j * ROWS + lane];
        float s = v * v;
        asm volatile("" : "+v"(s));
        a8[j] = s;
    }
#pragma unroll
    for (int i = 1; i < 8; ++i) {
#pragma unroll
        for (int j = 0; j < 8; ++j) {
            const float v = zs[(8 * i + j) * ROWS + lane];
            float s = v * v;
            asm volatile("" : "+v"(s));
            a8[j] += s;
        }
    }
    const float szz = ((a8[0] + a8[1]) + (a8[2] + a8[3]))
                    + ((a8[4] + a8[5]) + (a8[6] + a8[7]));

    const int c0 = w * SEG_C;
    float best = __builtin_inff();
    int bc = c0;

    for (int t = 0; t < SEG_C; t += NT) {          /* ascending code tiles */
        float acc[NT];
#pragma unroll
        for (int j = 0; j < NT; ++j) acc[j] = 0.0f;

#pragma unroll
        for (int kk = 0; kk < VQ_D; kk += KC) {    /* ascending k chunks */
            const float z0 = zs[(kk + 0) * ROWS + lane];
            const float z1 = zs[(kk + 1) * ROWS + lane];
            const float z2 = zs[(kk + 2) * ROWS + lane];
            const float z3 = zs[(kk + 3) * ROWS + lane];
#pragma unroll
            for (int j = 0; j < NT; ++j) {
                const float* __restrict__ ec = emb + ((c0 + t + j) << 6) + kk;
                /* same single-acc ascending-k chain, resumed across chunks */
                acc[j] = __builtin_fmaf(z0, ec[0], acc[j]);
                acc[j] = __builtin_fmaf(z1, ec[1], acc[j]);
                acc[j] = __builtin_fmaf(z2, ec[2], acc[j]);
                acc[j] = __builtin_fmaf(z3, ec[3], acc[j]);
            }
        }
#pragma unroll
        for (int j = 0; j < NT; ++j) {             /* ascending: first-index ties */
            const int c = c0 + t + j;
            const float dist = (szz - 2.0f * acc[j]) + nE[c];
            if (dist < best) { best = dist; bc = c; }
        }
    }
    cand[(size_t)w * VQ_R + r] = make_float2(best, (float)bc);
}

/* ---- merge 4 candidates, gather, write z_q + codes, loss partials ---- */
__global__ __launch_bounds__(MAIN_BLOCK) void vq_epilogue(
    const float* __restrict__ z, const float* __restrict__ emb,
    const float2* __restrict__ cand, float* __restrict__ out,
    float* __restrict__ partials)
{
    const int r = blockIdx.x * MAIN_BLOCK + threadIdx.x;
    const int b = r >> 12;
    const int l = r & (VQ_L - 1);

    float best = __builtin_inff();
    int bc = 0;
#pragma unroll
    for (int seg = 0; seg < NSEG; ++seg) {         /* ascending: ties -> first */
        const float2 cd = cand[(size_t)seg * VQ_R + r];
        if (cd.x < best) { best = cd.x; bc = (int)cd.y; }
    }

    const float* zp = z + ((size_t)b << 18) + l;
    const float* __restrict__ eb = emb + (bc << 6);
    float lsum = 0.0f;
#pragma unroll
    for (int d = 0; d < VQ_D; ++d) {
        const float q = eb[d];
        const float zd = zp[(size_t)d << 12];
        out[((size_t)b << 18) + ((size_t)d << 12) + l] = q;
        const float df = q - zd;
        lsum = __builtin_fmaf(df, df, lsum);
    }
    out[VQ_ZQ + 1 + (size_t)r] = (float)bc;

#pragma unroll
    for (int off = 32; off > 0; off >>= 1)
        lsum += __shfl_down(lsum, off, 64);
    __shared__ float wsum[MAIN_BLOCK / 64];
    const int lane = threadIdx.x & 63;
    const int wid = threadIdx.x >> 6;
    if (lane == 0) wsum[wid] = lsum;
    __syncthreads();
    if (threadIdx.x == 0)
        partials[blockIdx.x] = (wsum[0] + wsum[1]) + (wsum[2] + wsum[3]);
}

__global__ void vq_final(const float* __restrict__ partials, float* __restrict__ out) {
    if (threadIdx.x == 0 && blockIdx.x == 0) {
        float s = 0.0f;
        for (int i = 0; i < MAIN_GRID; ++i) s += partials[i];
        const float mse = s / (float)VQ_ZQ;
        out[VQ_ZQ] = mse + 0.25f * mse;   /* vq_loss + 0.25*commitment */
    }
}

extern "C" void kernel_launch(void* const* d_in, const int* in_sizes, int n_in,
                              void* d_out, int out_size, void* d_ws, size_t ws_size,
                              hipStream_t stream) {
    const float* z   = (const float*)d_in[0];
    const float* emb = (const float*)d_in[1];
    float* out = (float*)d_out;
    float* nE = (float*)d_ws;                       /* 1024 f  @ 0      */
    float* partials = nE + VQ_N;                    /* 512 f   @ 4096B  */
    float2* cand = (float2*)(partials + MAIN_GRID); /* 4*R f2  @ 6144B  */

    vq_norme<<<dim3(VQ_N / 256), dim3(256), 0, stream>>>(emb, nE);
    vq_dist<<<dim3(DGRID), dim3(4 * ROWS), 0, stream>>>(z, emb, nE, cand);
    vq_epilogue<<<dim3(MAIN_GRID), dim3(MAIN_BLOCK), 0, stream>>>(z, emb, cand, out, partials);
    vq_final<<<dim3(1), dim3(64), 0, stream>>>(partials, out);
}

// Round 8
// 307.798 us; speedup vs baseline: 3.1708x; 3.1708x over previous
//
#include <hip/hip_runtime.h>

#define VQ_B 32
#define VQ_D 64
#define VQ_L 4096
#define VQ_N 1024
#define VQ_R (VQ_B * VQ_L)            /* 131072 rows */
#define VQ_ZQ ((size_t)VQ_R * VQ_D)   /* 8388608 z_q elements */
#define MAIN_BLOCK 256
#define MAIN_GRID (VQ_R / MAIN_BLOCK) /* 512 (epilogue grid) */
#define NSEG 4
#define SEG_C (VQ_N / NSEG)           /* 256 codes per segment */
#define NT 16                         /* code-tile: 16 accumulators */
#define KC 4                          /* k-chunk: 4 z values live */
#define ROWS 64                       /* rows per block (= lanes) */
#define DGRID (VQ_R / ROWS)           /* 2048 row-blocks */

typedef __attribute__((ext_vector_type(16))) float f32x16;

/* ---- norm-of-embedding kernel (validated rounds 1-7, unchanged) ---- */
#define ZVE(i) ((i) < 16 ? zvA[(i) & 15] : (i) < 32 ? zvB[(i) & 15] \
               : (i) < 48 ? zvC[(i) & 15] : zvD[(i) & 15])
#define SQB(x) ({ float s_ = (x) * (x); asm volatile("" : "+v"(s_)); s_; })
#define NP_PAIRWISE64_SQ(dst)                                                  \
    do {                                                                       \
        float r0 = SQB(ZVE(0)), r1 = SQB(ZVE(1)), r2 = SQB(ZVE(2)),            \
              r3 = SQB(ZVE(3)), r4 = SQB(ZVE(4)), r5 = SQB(ZVE(5)),            \
              r6 = SQB(ZVE(6)), r7 = SQB(ZVE(7));                              \
        _Pragma("unroll")                                                      \
        for (int i_ = 1; i_ < 8; ++i_) {                                       \
            r0 += SQB(ZVE(8 * i_ + 0)); r1 += SQB(ZVE(8 * i_ + 1));            \
            r2 += SQB(ZVE(8 * i_ + 2)); r3 += SQB(ZVE(8 * i_ + 3));            \
            r4 += SQB(ZVE(8 * i_ + 4)); r5 += SQB(ZVE(8 * i_ + 5));            \
            r6 += SQB(ZVE(8 * i_ + 6)); r7 += SQB(ZVE(8 * i_ + 7));            \
        }                                                                      \
        dst = ((r0 + r1) + (r2 + r3)) + ((r4 + r5) + (r6 + r7));               \
    } while (0)

__global__ void vq_norme(const float* __restrict__ emb, float* __restrict__ nE) {
    const int c = blockIdx.x * blockDim.x + threadIdx.x;
    if (c >= VQ_N) return;
    const float* ec = emb + (c << 6);
    f32x16 zvA, zvB, zvC, zvD;
#pragma unroll
    for (int d = 0; d < 16; ++d) {
        zvA[d] = ec[d];
        zvB[d] = ec[d + 16];
        zvC[d] = ec[d + 32];
        zvD[d] = ec[d + 48];
    }
    float s;
    NP_PAIRWISE64_SQ(s);
    nE[c] = s;
}

/* ---- distance kernel: 4 waves share one 64-row z tile ----
   Block = 256 threads; wave w scans codebook segment w. Segment base is
   forced into an SGPR via readfirstlane (w IS wave-uniform; round 7
   showed the compiler can't prove it and demotes emb to per-lane VMEM
   loads, SGPR 112->32, 2.2x slower). With c0 scalar, emb and nE are
   s_loads on the scalar pipe again. Per-code arithmetic bitwise
   identical: numpy 8-acc szz (d = 8i+j ascending, squares rounded
   pre-add), single-acc strictly-ascending-k fmaf chain, strict-<
   ascending tie-break. zs[d][lane]: 2 lanes/bank, conflict-free. */
__global__ __launch_bounds__(4 * ROWS, 4) void vq_dist(
    const float* __restrict__ z, const float* __restrict__ emb,
    const float* __restrict__ nE, float2* __restrict__ cand)
{
    __shared__ float zs[VQ_D * ROWS];  /* 16 KB: [d][lane] */
    const int w = threadIdx.x >> 6;    /* wave = codebook segment */
    const int lane = threadIdx.x & 63;
    const int r = blockIdx.x * ROWS + lane;
    const int b = r >> 12;
    const int l = r & (VQ_L - 1);
    const float* zp = z + ((size_t)b << 18) + l;   /* z[b, d, l], d-stride 4096 */

    /* cooperative stage: wave w loads d in [16w, 16w+16), coalesced */
#pragma unroll
    for (int j = 0; j < 16; ++j) {
        const int d = (w << 4) + j;
        zs[d * ROWS + lane] = zp[(size_t)d << 12];
    }
    __syncthreads();

    /* szz from LDS, numpy 8-acc pairwise order (identical bits) */
    float a8[8];
#pragma unroll
    for (int j = 0; j < 8; ++j) {
        const float v = zs[j * ROWS + lane];
        float s = v * v;
        asm volatile("" : "+v"(s));
        a8[j] = s;
    }
#pragma unroll
    for (int i = 1; i < 8; ++i) {
#pragma unroll
        for (int j = 0; j < 8; ++j) {
            const float v = zs[(8 * i + j) * ROWS + lane];
            float s = v * v;
            asm volatile("" : "+v"(s));
            a8[j] += s;
        }
    }
    const float szz = ((a8[0] + a8[1]) + (a8[2] + a8[3]))
                    + ((a8[4] + a8[5]) + (a8[6] + a8[7]));

    /* SGPR segment base: value-preserving (w uniform across the wave) */
    const int c0 = __builtin_amdgcn_readfirstlane(w) * SEG_C;
    float best = __builtin_inff();
    int bc = c0;

    for (int t = 0; t < SEG_C; t += NT) {          /* ascending code tiles */
        float acc[NT];
#pragma unroll
        for (int j = 0; j < NT; ++j) acc[j] = 0.0f;

#pragma unroll
        for (int kk = 0; kk < VQ_D; kk += KC) {    /* ascending k chunks */
            const float z0 = zs[(kk + 0) * ROWS + lane];
            const float z1 = zs[(kk + 1) * ROWS + lane];
            const float z2 = zs[(kk + 2) * ROWS + lane];
            const float z3 = zs[(kk + 3) * ROWS + lane];
#pragma unroll
            for (int j = 0; j < NT; ++j) {
                const float* __restrict__ ec = emb + ((c0 + t + j) << 6) + kk;
                /* same single-acc ascending-k chain, resumed across chunks */
                acc[j] = __builtin_fmaf(z0, ec[0], acc[j]);
                acc[j] = __builtin_fmaf(z1, ec[1], acc[j]);
                acc[j] = __builtin_fmaf(z2, ec[2], acc[j]);
                acc[j] = __builtin_fmaf(z3, ec[3], acc[j]);
            }
        }
#pragma unroll
        for (int j = 0; j < NT; ++j) {             /* ascending: first-index ties */
            const int c = c0 + t + j;
            const float dist = (szz - 2.0f * acc[j]) + nE[c];
            if (dist < best) { best = dist; bc = c; }
        }
    }
    cand[(size_t)w * VQ_R + r] = make_float2(best, (float)bc);
}

/* ---- merge 4 candidates, gather, write z_q + codes, loss partials ---- */
__global__ __launch_bounds__(MAIN_BLOCK) void vq_epilogue(
    const float* __restrict__ z, const float* __restrict__ emb,
    const float2* __restrict__ cand, float* __restrict__ out,
    float* __restrict__ partials)
{
    const int r = blockIdx.x * MAIN_BLOCK + threadIdx.x;
    const int b = r >> 12;
    const int l = r & (VQ_L - 1);

    float best = __builtin_inff();
    int bc = 0;
#pragma unroll
    for (int seg = 0; seg < NSEG; ++seg) {         /* ascending: ties -> first */
        const float2 cd = cand[(size_t)seg * VQ_R + r];
        if (cd.x < best) { best = cd.x; bc = (int)cd.y; }
    }

    const float* zp = z + ((size_t)b << 18) + l;
    const float* __restrict__ eb = emb + (bc << 6);
    float lsum = 0.0f;
#pragma unroll
    for (int d = 0; d < VQ_D; ++d) {
        const float q = eb[d];
        const float zd = zp[(size_t)d << 12];
        out[((size_t)b << 18) + ((size_t)d << 12) + l] = q;
        const float df = q - zd;
        lsum = __builtin_fmaf(df, df, lsum);
    }
    out[VQ_ZQ + 1 + (size_t)r] = (float)bc;

#pragma unroll
    for (int off = 32; off > 0; off >>= 1)
        lsum += __shfl_down(lsum, off, 64);
    __shared__ float wsum[MAIN_BLOCK / 64];
    const int lane = threadIdx.x & 63;
    const int wid = threadIdx.x >> 6;
    if (lane == 0) wsum[wid] = lsum;
    __syncthreads();
    if (threadIdx.x == 0)
        partials[blockIdx.x] = (wsum[0] + wsum[1]) + (wsum[2] + wsum[3]);
}

__global__ void vq_final(const float* __restrict__ partials, float* __restrict__ out) {
    if (threadIdx.x == 0 && blockIdx.x == 0) {
        float s = 0.0f;
        for (int i = 0; i < MAIN_GRID; ++i) s += partials[i];
        const float mse = s / (float)VQ_ZQ;
        out[VQ_ZQ] = mse + 0.25f * mse;   /* vq_loss + 0.25*commitment */
    }
}

extern "C" void kernel_launch(void* const* d_in, const int* in_sizes, int n_in,
                              void* d_out, int out_size, void* d_ws, size_t ws_size,
                              hipStream_t stream) {
    const float* z   = (const float*)d_in[0];
    const float* emb = (const float*)d_in[1];
    float* out = (float*)d_out;
    float* nE = (float*)d_ws;                       /* 1024 f  @ 0      */
    float* partials = nE + VQ_N;                    /* 512 f   @ 4096B  */
    float2* cand = (float2*)(partials + MAIN_GRID); /* 4*R f2  @ 6144B  */

    vq_norme<<<dim3(VQ_N / 256), dim3(256), 0, stream>>>(emb, nE);
    vq_dist<<<dim3(DGRID), dim3(4 * ROWS), 0, stream>>>(z, emb, nE, cand);
    vq_epilogue<<<dim3(MAIN_GRID), dim3(MAIN_BLOCK), 0, stream>>>(z, emb, cand, out, partials);
    vq_final<<<dim3(1), dim3(64), 0, stream>>>(partials, out);
}